// Round 2
// baseline (537.439 us; speedup 1.0000x reference)
//
#include <hip/hip_runtime.h>
#include <math.h>

#define B_    4
#define NF    300
#define QD    512
#define HID   512
#define NH    8
#define HD    64
#define HW    6400      // 80*80
#define ROWS  2400      // NF*NH
#define NQP   384       // padded q rows per (b,n) block (3 tiles of 128)
#define NORM_FACT 0.125f
#define NEG_INF (-INFINITY)

typedef __bf16 bf16_t;
typedef __bf16 bf16x8_t __attribute__((ext_vector_type(8)));
typedef float  f32x4    __attribute__((ext_vector_type(4)));
typedef unsigned int u32;

__device__ __forceinline__ void splitf(float x, bf16_t& h, bf16_t& l) {
    h = (bf16_t)x;
    l = (bf16_t)(x - (float)h);
}
// swizzle: permute 16B c-blocks within a 128B (64-elem) chunk by row&7
__device__ __forceinline__ int swz(int c, int row) {
    return (((c >> 3) ^ (row & 7)) << 3) | (c & 7);
}
// async 16B global->LDS copy (lds must be the wave-uniform base; HW adds lane*16)
__device__ __forceinline__ void gload_lds16(const bf16_t* g, bf16_t* l) {
    __builtin_amdgcn_global_load_lds(
        (const __attribute__((address_space(1))) u32*)g,
        (__attribute__((address_space(3))) u32*)l, 16, 0, 0);
}

// ---------------- K1: presplit — K transpose+split, W split, qproj ---------
// blocks [0,3200): K[b][d][p] -> Kt_hi/lo [b][p][d swz-per-64chunk]
// blocks [3200,3328): W -> Wh/Wl [e][d swz-per-64chunk]
// blocks [3328,3628): qproj -> qh_hi/lo [b][n][q][64c swz]
__global__ __launch_bounds__(256) void presplit_kernel(
    const float* __restrict__ k, const float* __restrict__ kw,
    const float* __restrict__ q, const float* __restrict__ qw,
    const float* __restrict__ qb,
    bf16_t* __restrict__ kt_hi, bf16_t* __restrict__ kt_lo,
    bf16_t* __restrict__ wh, bf16_t* __restrict__ wl,
    bf16_t* __restrict__ qh_hi, bf16_t* __restrict__ qh_lo)
{
    __shared__ __align__(16) char smem[64 * 65 * 4];
    const int blk = blockIdx.x;
    const int t   = threadIdx.x;

    if (blk < 3200) {
        // ---- K transpose+split: 64d x 64p tile ----
        float (*ts)[65] = (float (*)[65])smem;   // [d-local][p-local]
        const int b   = blk / 800;
        const int rem = blk % 800;
        const int d0  = (rem / 100) * 64;
        const int p0  = (rem % 100) * 64;
        const float* kB = k + (size_t)b * QD * HW;
        const int c = t & 63, r0 = t >> 6;
        #pragma unroll
        for (int pass = 0; pass < 16; ++pass) {
            const int r = r0 + pass * 4;
            ts[r][c] = kB[(size_t)(d0 + r) * HW + p0 + c];
        }
        __syncthreads();
        const int pr  = t >> 2;
        const int dcb = (t & 3) * 16;
        const int pg  = p0 + pr;
        const size_t obase = ((size_t)b * HW + pg) * 512 + d0;
        #pragma unroll
        for (int half = 0; half < 2; ++half) {
            const int c0 = dcb + half * 8;        // aligned-8 run
            bf16x8_t hv, lv;
            #pragma unroll
            for (int j = 0; j < 8; ++j) {
                bf16_t h, l; splitf(ts[c0 + j][pr], h, l);
                hv[j] = h; lv[j] = l;
            }
            const size_t o = obase + ((((c0 >> 3) ^ (pg & 7)) << 3));
            *(bf16x8_t*)&kt_hi[o] = hv;
            *(bf16x8_t*)&kt_lo[o] = lv;
        }
    } else if (blk < 3328) {
        // ---- W split (rows already d-contiguous) ----
        const int base = (blk - 3200) * 2048 + t * 8;
        const int e = base >> 9, d = base & 511;
        float4 v0 = *(const float4*)&kw[base];
        float4 v1 = *(const float4*)&kw[base + 4];
        bf16x8_t hv, lv; bf16_t h, l;
        splitf(v0.x, h, l); hv[0] = h; lv[0] = l;
        splitf(v0.y, h, l); hv[1] = h; lv[1] = l;
        splitf(v0.z, h, l); hv[2] = h; lv[2] = l;
        splitf(v0.w, h, l); hv[3] = h; lv[3] = l;
        splitf(v1.x, h, l); hv[4] = h; lv[4] = l;
        splitf(v1.y, h, l); hv[5] = h; lv[5] = l;
        splitf(v1.z, h, l); hv[6] = h; lv[6] = l;
        splitf(v1.w, h, l); hv[7] = h; lv[7] = l;
        const size_t o = (size_t)e * 512 + (d & ~63)
                       + (((((d >> 3) & 7) ^ (e & 7)) << 3));
        *(bf16x8_t*)&wh[o] = hv;
        *(bf16x8_t*)&wl[o] = lv;
    } else {
        // ---- qproj: 4 q-rows per block ----
        float (*qs)[QD] = (float (*)[QD])smem;
        const int r0    = (blk - 3328) * 4;       // rows in (b*NF+q) space
        const int b     = r0 / NF;
        const int qbase = r0 % NF;
        #pragma unroll
        for (int row = 0; row < 4; ++row) {
            qs[row][t]       = q[(size_t)(r0 + row) * QD + t];
            qs[row][t + 256] = q[(size_t)(r0 + row) * QD + t + 256];
        }
        __syncthreads();
        #pragma unroll
        for (int eo = 0; eo < 2; ++eo) {
            const int e = t + eo * 256;
            const int n = e >> 6, c = e & 63;
            float a[4] = {0.f, 0.f, 0.f, 0.f};
            for (int d = 0; d < QD; d += 4) {
                float4 w = *(const float4*)&qw[(size_t)e * QD + d];
                #pragma unroll
                for (int row = 0; row < 4; ++row)
                    a[row] += qs[row][d]*w.x + qs[row][d+1]*w.y
                            + qs[row][d+2]*w.z + qs[row][d+3]*w.w;
            }
            const float bias = qb[e];
            #pragma unroll
            for (int row = 0; row < 4; ++row) {
                const int qq = qbase + row;
                const float val = (a[row] + bias) * NORM_FACT;
                bf16_t h, l; splitf(val, h, l);
                size_t off = ((size_t)(b * NH + n) * NQP + qq) * 64 + swz(c, qq);
                qh_hi[off] = h; qh_lo[off] = l;
            }
        }
    }
}

// ---------------- K2: kproj — pure-copy staging + split-bf16 MFMA ----------
// C'[p][e] = Kt[p][d] * W[e][d]^T + kb; stored [b][n][p][64c swz]
__global__ __launch_bounds__(256, 2) void kproj_mfma(
    const bf16_t* __restrict__ kt_hi, const bf16_t* __restrict__ kt_lo,
    const bf16_t* __restrict__ wh, const bf16_t* __restrict__ wl,
    const float* __restrict__ kb, bf16_t* __restrict__ kp_hi,
    bf16_t* __restrict__ kp_lo)
{
    __shared__ __align__(16) bf16_t Ah[128 * 64];   // Kt rows [p][64d swz]
    __shared__ __align__(16) bf16_t Al[128 * 64];
    __shared__ __align__(16) bf16_t Bh[128 * 64];   // W rows  [e][64d swz]
    __shared__ __align__(16) bf16_t Bl[128 * 64];
    const int b  = blockIdx.z;
    const int e0 = blockIdx.y * 128;
    const int p0 = blockIdx.x * 128;
    const int t  = threadIdx.x;
    const int wave = t >> 6, lane = t & 63;
    const int wr = wave >> 1, wc = wave & 1;        // wr: p-half, wc: e-half
    const int lm = lane & 15, lq = lane >> 4;
    const int wu = t & ~63;                          // wave-uniform lane base

    f32x4 acc[4][4];
    const f32x4 zero4 = {0.f, 0.f, 0.f, 0.f};
    #pragma unroll
    for (int i = 0; i < 4; ++i)
        #pragma unroll
        for (int j = 0; j < 4; ++j) acc[i][j] = zero4;

    const size_t abase = ((size_t)b * HW + p0) * 512;

    for (int d0 = 0; d0 < QD; d0 += 64) {
        // stage 4 planes x 16KB as pure async 16B copies
        #pragma unroll
        for (int i = 0; i < 4; ++i) {
            const int u   = i * 256 + t;            // uint4 index 0..1023
            const int ub  = i * 256 + wu;           // wave-uniform base
            const int row = u >> 3;
            const int c8  = (u & 7) * 8;
            const size_t ga = abase + (size_t)row * 512 + d0 + c8;
            const size_t gb = (size_t)(e0 + row) * 512 + d0 + c8;
            gload_lds16(kt_hi + ga, &Ah[(size_t)ub * 8]);
            gload_lds16(kt_lo + ga, &Al[(size_t)ub * 8]);
            gload_lds16(wh + gb,    &Bh[(size_t)ub * 8]);
            gload_lds16(wl + gb,    &Bl[(size_t)ub * 8]);
        }
        __syncthreads();

        #pragma unroll
        for (int ks = 0; ks < 2; ++ks) {
            bf16x8_t ah[4], al[4], bh[4], bl[4];
            #pragma unroll
            for (int mt = 0; mt < 4; ++mt) {
                const int r   = wr * 64 + mt * 16 + lm;
                const int off = r * 64 + (((ks * 4 + lq) ^ (lm & 7)) << 3);
                ah[mt] = *(const bf16x8_t*)&Ah[off];
                al[mt] = *(const bf16x8_t*)&Al[off];
            }
            #pragma unroll
            for (int nt = 0; nt < 4; ++nt) {
                const int r   = wc * 64 + nt * 16 + lm;
                const int off = r * 64 + (((ks * 4 + lq) ^ (lm & 7)) << 3);
                bh[nt] = *(const bf16x8_t*)&Bh[off];
                bl[nt] = *(const bf16x8_t*)&Bl[off];
            }
            #pragma unroll
            for (int mt = 0; mt < 4; ++mt)
                #pragma unroll
                for (int nt = 0; nt < 4; ++nt) {
                    f32x4 a = acc[mt][nt];
                    a = __builtin_amdgcn_mfma_f32_16x16x32_bf16(al[mt], bh[nt], a, 0, 0, 0);
                    a = __builtin_amdgcn_mfma_f32_16x16x32_bf16(ah[mt], bl[nt], a, 0, 0, 0);
                    a = __builtin_amdgcn_mfma_f32_16x16x32_bf16(ah[mt], bh[nt], a, 0, 0, 0);
                    acc[mt][nt] = a;
                }
        }
        __syncthreads();
    }

    // epilogue: lane axis = e (col), reg axis = p (row) -> c-contiguous stores
    #pragma unroll
    for (int nt = 0; nt < 4; ++nt) {
        const int e = e0 + wc * 64 + nt * 16 + lm;
        const int n = e >> 6;
        const int c = (nt * 16 + lm) & 63;     // == e & 63
        const float bias = kb[e];
        bf16_t* dh = kp_hi + (size_t)(b * NH + n) * HW * 64;
        bf16_t* dl = kp_lo + (size_t)(b * NH + n) * HW * 64;
        #pragma unroll
        for (int mt = 0; mt < 4; ++mt) {
            #pragma unroll
            for (int reg = 0; reg < 4; ++reg) {
                int p = p0 + wr * 64 + mt * 16 + lq * 4 + reg;
                float val = acc[mt][nt][reg] + bias;
                bf16_t h, l; splitf(val, h, l);
                size_t off = (size_t)p * 64 + swz(c, p);
                dh[off] = h; dl[off] = l;
            }
        }
    }
}

// ---------------- score-pass helpers (operand-swapped: A=kp, B=qh) ---------
template<int KS>
__device__ __forceinline__ void load_qf(const bf16_t* __restrict__ qp,
                                        int lm, int lq, bf16x8_t (&f)[4])
{
    #pragma unroll
    for (int nt = 0; nt < 4; ++nt) {
        const size_t o = (size_t)(nt * 16 + lm) * 64
                       + (size_t)((((KS * 4 + lq) ^ (lm & 7))) << 3);
        f[nt] = *(const bf16x8_t*)(qp + o);
    }
}

template<int KS>
__device__ __forceinline__ void ks_mfma_hi(const bf16_t* Kh, int wr, int lm, int lq,
                                           const bf16x8_t (&qh)[4], f32x4 (&acc)[4][4])
{
    #pragma unroll
    for (int mt = 0; mt < 4; ++mt) {
        const int row = wr * 64 + mt * 16 + lm;
        const int off = row * 64 + ((((KS * 4 + lq) ^ (lm & 7))) << 3);
        const bf16x8_t ah = *(const bf16x8_t*)&Kh[off];
        #pragma unroll
        for (int nt = 0; nt < 4; ++nt)
            acc[mt][nt] = __builtin_amdgcn_mfma_f32_16x16x32_bf16(
                ah, qh[nt], acc[mt][nt], 0, 0, 0);
    }
}

template<int KS>
__device__ __forceinline__ void ks_mfma_split(const bf16_t* Kh, const bf16_t* Kl,
                                              int wr, int lm, int lq,
                                              const bf16x8_t (&qh)[4],
                                              const bf16x8_t (&ql)[4],
                                              f32x4 (&acc)[4][4])
{
    #pragma unroll
    for (int mt = 0; mt < 4; ++mt) {
        const int row = wr * 64 + mt * 16 + lm;
        const int off = row * 64 + ((((KS * 4 + lq) ^ (lm & 7))) << 3);
        const bf16x8_t ah = *(const bf16x8_t*)&Kh[off];
        const bf16x8_t al = *(const bf16x8_t*)&Kl[off];
        #pragma unroll
        for (int nt = 0; nt < 4; ++nt) {
            f32x4 a = acc[mt][nt];
            a = __builtin_amdgcn_mfma_f32_16x16x32_bf16(al, qh[nt], a, 0, 0, 0);
            a = __builtin_amdgcn_mfma_f32_16x16x32_bf16(ah, ql[nt], a, 0, 0, 0);
            a = __builtin_amdgcn_mfma_f32_16x16x32_bf16(ah, qh[nt], a, 0, 0, 0);
            acc[mt][nt] = a;
        }
    }
}

// ---------------- K3a: pass A — hi-plane bf16 score GEMM, (m,s) partials ----
__global__ __launch_bounds__(256, 4) void scores_pass_a(
    const bf16_t* __restrict__ qh_hi, const bf16_t* __restrict__ kp_hi,
    const int* __restrict__ mask, float* __restrict__ partials)
{
    __shared__ __align__(16) bf16_t Kh[128 * 64];   // kp_hi tile [p][c swz]
    __shared__ float redM[256];
    __shared__ float redS[256];
    const int z  = blockIdx.z;
    const int b  = z >> 3, n = z & 7;
    const int q0 = blockIdx.y * 128;
    const int p0 = blockIdx.x * 128;
    const int t  = threadIdx.x;
    const int wave = t >> 6, lane = t & 63;
    const int wr = wave >> 1, wc = wave & 1;        // wr: p-half, wc: q-half
    const int lm = lane & 15, lq = lane >> 4;
    const int wu = t & ~63;
    const bool wave_active = (q0 + wc * 64) < NF;

    // stage kp_hi tile via async 16B copies
    const bf16_t* gb = kp_hi + ((size_t)(b * NH + n) * HW + p0) * 64;
    #pragma unroll
    for (int i = 0; i < 4; ++i)
        gload_lds16(gb + (size_t)(i * 256 + t) * 8, &Kh[(size_t)(i * 256 + wu) * 8]);

    const bf16_t* qph = qh_hi + ((size_t)(b * NH + n) * NQP + q0 + wc * 64) * 64;
    bf16x8_t qf0[4];
    if (wave_active) load_qf<0>(qph, lm, lq, qf0);   // overlap staging drain
    __syncthreads();

    float tm = NEG_INF, ts = 0.f;
    if (wave_active) {
        f32x4 acc[4][4];
        const f32x4 zero4 = {0.f, 0.f, 0.f, 0.f};
        #pragma unroll
        for (int i = 0; i < 4; ++i)
            #pragma unroll
            for (int j = 0; j < 4; ++j) acc[i][j] = zero4;

        bf16x8_t qf1[4];
        load_qf<1>(qph, lm, lq, qf1);
        ks_mfma_hi<0>(Kh, wr, lm, lq, qf0, acc);
        ks_mfma_hi<1>(Kh, wr, lm, lq, qf1, acc);

        int4 mm4[4];
        #pragma unroll
        for (int mt = 0; mt < 4; ++mt)
            mm4[mt] = *(const int4*)&mask[b * HW + p0 + wr * 64 + mt * 16 + lq * 4];

        #pragma unroll
        for (int nt = 0; nt < 4; ++nt) {
            if (q0 + wc * 64 + nt * 16 + lm < NF) {
                #pragma unroll
                for (int mt = 0; mt < 4; ++mt)
                    #pragma unroll
                    for (int reg = 0; reg < 4; ++reg)
                        if (!((const int*)&mm4[mt])[reg])
                            tm = fmaxf(tm, acc[mt][nt][reg]);
            }
        }
        if (tm != NEG_INF) {
            #pragma unroll
            for (int nt = 0; nt < 4; ++nt) {
                if (q0 + wc * 64 + nt * 16 + lm < NF) {
                    #pragma unroll
                    for (int mt = 0; mt < 4; ++mt)
                        #pragma unroll
                        for (int reg = 0; reg < 4; ++reg)
                            if (!((const int*)&mm4[mt])[reg])
                                ts += __expf(acc[mt][nt][reg] - tm);
                }
            }
        }
    }

    redM[t] = tm; redS[t] = ts;
    __syncthreads();
    for (int off = 128; off > 0; off >>= 1) {
        if (t < off) {
            float m1 = redM[t],       s1 = redS[t];
            float m2 = redM[t + off], s2 = redS[t + off];
            float M = fmaxf(m1, m2);
            float s = (M == NEG_INF) ? 0.f
                      : (s1 * __expf(m1 - M) + s2 * __expf(m2 - M));
            redM[t] = M; redS[t] = s;
        }
        __syncthreads();
    }
    if (t == 0) {
        int lin = (z * gridDim.y + blockIdx.y) * gridDim.x + blockIdx.x;
        partials[2 * lin]     = redM[0];
        partials[2 * lin + 1] = redS[0];
    }
}

// ---------------- K4: merge partials per batch -> (M_b, 1/S_b) -------------
__global__ __launch_bounds__(256) void stats_kernel(
    const float* __restrict__ partials, float* __restrict__ stats, int nper)
{
    __shared__ float redM[256];
    __shared__ float redS[256];
    const int b = blockIdx.x, t = threadIdx.x;
    const float* p = partials + (size_t)b * nper * 2;
    float m = NEG_INF, s = 0.f;
    for (int i = t; i < nper; i += 256) {
        float m2 = p[2 * i], s2 = p[2 * i + 1];
        float M = fmaxf(m, m2);
        float ns = (M == NEG_INF) ? 0.f
                   : (s * __expf(m - M) + s2 * __expf(m2 - M));
        m = M; s = ns;
    }
    redM[t] = m; redS[t] = s;
    __syncthreads();
    for (int off = 128; off > 0; off >>= 1) {
        if (t < off) {
            float m1 = redM[t],       s1 = redS[t];
            float m2 = redM[t + off], s2 = redS[t + off];
            float M = fmaxf(m1, m2);
            float ns = (M == NEG_INF) ? 0.f
                       : (s1 * __expf(m1 - M) + s2 * __expf(m2 - M));
            redM[t] = M; redS[t] = ns;
        }
        __syncthreads();
    }
    if (t == 0) {
        stats[2 * b]     = redM[0];
        stats[2 * b + 1] = 1.0f / redS[0];
    }
}

// ---------------- K3b: pass B — split-bf16 score GEMM, write exp(s-M)/S ----
__global__ __launch_bounds__(256, 3) void scores_pass_b(
    const bf16_t* __restrict__ qh_hi, const bf16_t* __restrict__ qh_lo,
    const bf16_t* __restrict__ kp_hi, const bf16_t* __restrict__ kp_lo,
    const int* __restrict__ mask, const float* __restrict__ stats,
    float* __restrict__ out)
{
    __shared__ __align__(16) bf16_t Kh[128 * 64];   // kp tiles [p][c swz]
    __shared__ __align__(16) bf16_t Kl[128 * 64];
    const int z  = blockIdx.z;
    const int b  = z >> 3, n = z & 7;
    const int q0 = blockIdx.y * 128;
    const int p0 = blockIdx.x * 128;
    const int t  = threadIdx.x;
    const int wave = t >> 6, lane = t & 63;
    const int wr = wave >> 1, wc = wave & 1;        // wr: p-half, wc: q-half
    const int lm = lane & 15, lq = lane >> 4;
    const int wu = t & ~63;
    const bool wave_active = (q0 + wc * 64) < NF;

    const float M    = stats[2 * b];
    const float invS = stats[2 * b + 1];

    const size_t bbase = ((size_t)(b * NH + n) * HW + p0) * 64;
    const bf16_t* gbh = kp_hi + bbase;
    const bf16_t* gbl = kp_lo + bbase;
    #pragma unroll
    for (int i = 0; i < 4; ++i) {
        gload_lds16(gbh + (size_t)(i * 256 + t) * 8, &Kh[(size_t)(i * 256 + wu) * 8]);
        gload_lds16(gbl + (size_t)(i * 256 + t) * 8, &Kl[(size_t)(i * 256 + wu) * 8]);
    }

    const size_t qoff = ((size_t)(b * NH + n) * NQP + q0 + wc * 64) * 64;
    const bf16_t* qph = qh_hi + qoff;
    const bf16_t* qpl = qh_lo + qoff;
    bf16x8_t qh0[4], ql0[4];
    if (wave_active) {                 // issue before the barrier drain
        load_qf<0>(qph, lm, lq, qh0);
        load_qf<0>(qpl, lm, lq, ql0);
    }
    __syncthreads();
    if (!wave_active) return;          // no further barriers in this kernel

    f32x4 acc[4][4];
    const f32x4 zero4 = {0.f, 0.f, 0.f, 0.f};
    #pragma unroll
    for (int i = 0; i < 4; ++i)
        #pragma unroll
        for (int j = 0; j < 4; ++j) acc[i][j] = zero4;

    bf16x8_t qh1[4], ql1[4];
    load_qf<1>(qph, lm, lq, qh1);      // latency covered by ks=0 MFMAs
    load_qf<1>(qpl, lm, lq, ql1);
    ks_mfma_split<0>(Kh, Kl, wr, lm, lq, qh0, ql0, acc);
    ks_mfma_split<1>(Kh, Kl, wr, lm, lq, qh1, ql1, acc);

    int4 mm4[4];
    #pragma unroll
    for (int mt = 0; mt < 4; ++mt)
        mm4[mt] = *(const int4*)&mask[b * HW + p0 + wr * 64 + mt * 16 + lq * 4];

    #pragma unroll
    for (int nt = 0; nt < 4; ++nt) {
        const int qg = q0 + wc * 64 + nt * 16 + lm;
        if (qg < NF) {
            float* rowp = out + (size_t)(b * ROWS + qg * NH + n) * HW + p0 + wr * 64;
            #pragma unroll
            for (int mt = 0; mt < 4; ++mt) {
                f32x4 v;
                #pragma unroll
                for (int reg = 0; reg < 4; ++reg) {
                    const int msk = ((const int*)&mm4[mt])[reg];
                    v[reg] = msk ? 0.f : __expf(acc[mt][nt][reg] - M) * invS;
                }
                __builtin_nontemporal_store(v, (f32x4*)(rowp + mt * 16 + lq * 4));
            }
        }
    }
}

extern "C" void kernel_launch(void* const* d_in, const int* in_sizes, int n_in,
                              void* d_out, int out_size, void* d_ws, size_t ws_size,
                              hipStream_t stream) {
    const float* q    = (const float*)d_in[0];  // [4,300,512]
    const float* k    = (const float*)d_in[1];  // [4,512,80,80]
    const int*   mask = (const int*)  d_in[2];  // [4,80,80]
    const float* qw   = (const float*)d_in[3];  // [512,512]
    const float* qb   = (const float*)d_in[4];  // [512]
    const float* kw   = (const float*)d_in[5];  // [512,512]
    const float* kb   = (const float*)d_in[6];  // [512]
    float* out = (float*)d_out;                 // [4,1,2400,80,80]

    // workspace layout (bf16 planes + fp32 reductions), ~55.6 MB
    bf16_t* kp_hi = (bf16_t*)d_ws;
    bf16_t* kp_lo = kp_hi + (size_t)B_ * NH * HW * 64;
    bf16_t* qh_hi = kp_lo + (size_t)B_ * NH * HW * 64;
    bf16_t* qh_lo = qh_hi + (size_t)B_ * NH * NQP * 64;
    float* partials = (float*)(qh_lo + (size_t)B_ * NH * NQP * 64);
    float* stats    = partials + 2 * 4800;

    // scratch planes live in d_out (53.5 MB of 245.8 MB); fully consumed by
    // kproj_mfma before scores_pass_b overwrites out (stream-ordered).
    bf16_t* kt_hi = (bf16_t*)d_out;
    bf16_t* kt_lo = kt_hi + (size_t)B_ * HW * 512;
    bf16_t* wh    = kt_lo + (size_t)B_ * HW * 512;
    bf16_t* wl    = wh + (size_t)512 * 512;

    presplit_kernel<<<3628, 256, 0, stream>>>(k, kw, q, qw, qb,
                                              kt_hi, kt_lo, wh, wl, qh_hi, qh_lo);
    kproj_mfma<<<dim3(50, 4, 4), 256, 0, stream>>>(kt_hi, kt_lo, wh, wl, kb,
                                                   kp_hi, kp_lo);
    scores_pass_a<<<dim3(50, 3, 32), 256, 0, stream>>>(qh_hi, kp_hi, mask, partials);
    stats_kernel<<<4, 256, 0, stream>>>(partials, stats, 1200);
    scores_pass_b<<<dim3(50, 3, 32), 256, 0, stream>>>(qh_hi, qh_lo, kp_hi, kp_lo,
                                                       mask, stats, out);
}

// Round 3
// 482.592 us; speedup vs baseline: 1.1137x; 1.1137x over previous
//
#include <hip/hip_runtime.h>
#include <math.h>

#define B_    4
#define NF    300
#define QD    512
#define HID   512
#define NH    8
#define HD    64
#define HW    6400      // 80*80
#define ROWS  2400      // NF*NH
#define NQP   384       // padded q rows per (b,n) block (3 tiles of 128)
#define NORM_FACT 0.125f
#define NEG_INF (-INFINITY)
#define LDK   40        // padded LDS row (bf16) for kproj 32-wide k-chunks

typedef __bf16 bf16_t;
typedef __bf16 bf16x4_t __attribute__((ext_vector_type(4)));
typedef __bf16 bf16x8_t __attribute__((ext_vector_type(8)));
typedef float  f32x4    __attribute__((ext_vector_type(4)));

__device__ __forceinline__ void splitf(float x, bf16_t& h, bf16_t& l) {
    h = (bf16_t)x;
    l = (bf16_t)(x - (float)h);
}
// swizzle: permute 16B c-blocks within a 128B row by row&7 (conflict-free frags)
__device__ __forceinline__ int swz(int c, int row) {
    return (((c >> 3) ^ (row & 7)) << 3) | (c & 7);
}

// ---------------- merged projection kernel bodies --------------------------
// qproj: q projection -> bf16 hi/lo planes [b][n][q][64c swz]
__device__ __forceinline__ void qproj_body(
    char* smem, int blk, const float* __restrict__ q,
    const float* __restrict__ qw, const float* __restrict__ qb,
    bf16_t* __restrict__ qh_hi, bf16_t* __restrict__ qh_lo)
{
    float (*qs)[QD] = (float (*)[QD])smem;
    const int r0    = blk * 4;                 // rows in (b*NF+q) space; NF%4==0
    const int b     = r0 / NF;
    const int qbase = r0 % NF;
    const int t     = threadIdx.x;
    #pragma unroll
    for (int row = 0; row < 4; ++row) {
        qs[row][t]       = q[(size_t)(r0 + row) * QD + t];
        qs[row][t + 256] = q[(size_t)(r0 + row) * QD + t + 256];
    }
    __syncthreads();
    #pragma unroll
    for (int eo = 0; eo < 2; ++eo) {
        const int e = t + eo * 256;
        const int n = e >> 6, c = e & 63;
        float a[4] = {0.f, 0.f, 0.f, 0.f};
        for (int d = 0; d < QD; d += 4) {
            float4 w = *(const float4*)&qw[(size_t)e * QD + d];
            #pragma unroll
            for (int row = 0; row < 4; ++row)
                a[row] += qs[row][d]*w.x + qs[row][d+1]*w.y
                        + qs[row][d+2]*w.z + qs[row][d+3]*w.w;
        }
        const float bias = qb[e];
        #pragma unroll
        for (int row = 0; row < 4; ++row) {
            const int qq = qbase + row;
            const float val = (a[row] + bias) * NORM_FACT;
            bf16_t h, l; splitf(val, h, l);
            size_t off = ((size_t)(b * NH + n) * NQP + qq) * 64 + swz(c, qq);
            qh_hi[off] = h; qh_lo[off] = l;
        }
    }
}

// kproj: k projection (M=p, N=e) -> bf16 hi/lo planes [b][n][p][64c swz]
__device__ __forceinline__ void kproj_body(
    char* smem, int px, int ey, int b, const float* __restrict__ k,
    const float* __restrict__ kw, const float* __restrict__ kb,
    bf16_t* __restrict__ kp_hi, bf16_t* __restrict__ kp_lo)
{
    bf16_t (*Ah)[LDK] = (bf16_t (*)[LDK])(smem);            // K^T rows: [p][d]
    bf16_t (*Al)[LDK] = (bf16_t (*)[LDK])(smem + 10240);
    bf16_t (*Bh)[LDK] = (bf16_t (*)[LDK])(smem + 20480);    // W rows:   [e][d]
    bf16_t (*Bl)[LDK] = (bf16_t (*)[LDK])(smem + 30720);
    const int e0 = ey * 128;
    const int p0 = px * 128;
    const int t  = threadIdx.x;
    const int wave = t >> 6, lane = t & 63;
    const int wr = wave >> 1, wc = wave & 1;       // wr: p-half, wc: e-half
    const int lm = lane & 15, lq = lane >> 4;
    const float* kB = k + (size_t)b * QD * HW;

    f32x4 acc[4][4];
    const f32x4 zero4 = {0.f, 0.f, 0.f, 0.f};
    #pragma unroll
    for (int i = 0; i < 4; ++i)
        #pragma unroll
        for (int j = 0; j < 4; ++j) acc[i][j] = zero4;

    for (int d0 = 0; d0 < QD; d0 += 32) {
        // A = K^T: transpose-stage K[d][p] -> LDS [p][d]
        #pragma unroll
        for (int i = 0; i < 4; ++i) {
            int idx = t + i * 256;
            int p = idx & 127, db = (idx >> 7) << 2;
            bf16x4_t hv, lv;
            #pragma unroll
            for (int j = 0; j < 4; ++j) {
                float x = kB[(size_t)(d0 + db + j) * HW + p0 + p];
                bf16_t hx, lx; splitf(x, hx, lx);
                hv[j] = hx; lv[j] = lx;
            }
            *(bf16x4_t*)&Ah[p][db] = hv;
            *(bf16x4_t*)&Al[p][db] = lv;
        }
        // B = W: rows are already d-contiguous
        #pragma unroll
        for (int i = 0; i < 4; ++i) {
            int idx = t + i * 256;
            int e = idx >> 3, dp = (idx & 7) << 2;
            float4 v = *(const float4*)&kw[(size_t)(e0 + e) * QD + d0 + dp];
            bf16x4_t hv, lv; bf16_t hx, lx;
            splitf(v.x, hx, lx); hv[0] = hx; lv[0] = lx;
            splitf(v.y, hx, lx); hv[1] = hx; lv[1] = lx;
            splitf(v.z, hx, lx); hv[2] = hx; lv[2] = lx;
            splitf(v.w, hx, lx); hv[3] = hx; lv[3] = lx;
            *(bf16x4_t*)&Bh[e][dp] = hv;
            *(bf16x4_t*)&Bl[e][dp] = lv;
        }
        __syncthreads();

        bf16x8_t ah[4], al[4], bh[4], bl[4];
        #pragma unroll
        for (int mt = 0; mt < 4; ++mt) {
            int r = wr * 64 + mt * 16 + lm;
            ah[mt] = *(const bf16x8_t*)&Ah[r][lq * 8];
            al[mt] = *(const bf16x8_t*)&Al[r][lq * 8];
        }
        #pragma unroll
        for (int nt = 0; nt < 4; ++nt) {
            int c = wc * 64 + nt * 16 + lm;
            bh[nt] = *(const bf16x8_t*)&Bh[c][lq * 8];
            bl[nt] = *(const bf16x8_t*)&Bl[c][lq * 8];
        }
        #pragma unroll
        for (int mt = 0; mt < 4; ++mt)
            #pragma unroll
            for (int nt = 0; nt < 4; ++nt) {
                f32x4 a = acc[mt][nt];
                a = __builtin_amdgcn_mfma_f32_16x16x32_bf16(al[mt], bh[nt], a, 0, 0, 0);
                a = __builtin_amdgcn_mfma_f32_16x16x32_bf16(ah[mt], bl[nt], a, 0, 0, 0);
                a = __builtin_amdgcn_mfma_f32_16x16x32_bf16(ah[mt], bh[nt], a, 0, 0, 0);
                acc[mt][nt] = a;
            }
        __syncthreads();
    }

    // epilogue: lane axis = e (col), reg axis = p (row) -> c-contiguous stores
    #pragma unroll
    for (int nt = 0; nt < 4; ++nt) {
        const int e = e0 + wc * 64 + nt * 16 + lm;
        const int n = e >> 6;
        const int c = (nt * 16 + lm) & 63;     // == e & 63
        const float bias = kb[e];
        bf16_t* dh = kp_hi + (size_t)(b * NH + n) * HW * 64;
        bf16_t* dl = kp_lo + (size_t)(b * NH + n) * HW * 64;
        #pragma unroll
        for (int mt = 0; mt < 4; ++mt) {
            #pragma unroll
            for (int reg = 0; reg < 4; ++reg) {
                int p = p0 + wr * 64 + mt * 16 + lq * 4 + reg;
                float val = acc[mt][nt][reg] + bias;
                bf16_t h, l; splitf(val, h, l);
                size_t off = (size_t)p * 64 + swz(c, p);
                dh[off] = h; dl[off] = l;
            }
        }
    }
}

// merged: kproj blocks first (long pole), qproj blocks fill the tail
__global__ __launch_bounds__(256) void proj_kernel(
    const float* __restrict__ q, const float* __restrict__ qw,
    const float* __restrict__ qb, const float* __restrict__ k,
    const float* __restrict__ kw, const float* __restrict__ kb,
    bf16_t* __restrict__ qh_hi, bf16_t* __restrict__ qh_lo,
    bf16_t* __restrict__ kp_hi, bf16_t* __restrict__ kp_lo)
{
    __shared__ __align__(16) char smem[40960];
    const int bx = blockIdx.x;
    if (bx < 800) {
        kproj_body(smem, bx % 50, (bx / 50) % 4, bx / 200, k, kw, kb, kp_hi, kp_lo);
    } else {
        qproj_body(smem, bx - 800, q, qw, qb, qh_hi, qh_lo);
    }
}

// ---------------- score-pass helpers (operand-swapped: A=kp, B=qh) ---------
// qh fragment loads straight from global (L1/L2-hot, shared by 50 p-blocks)
template<int KS>
__device__ __forceinline__ void load_qf(const bf16_t* __restrict__ qp,
                                        int lm, int lq, bf16x8_t (&f)[4])
{
    #pragma unroll
    for (int nt = 0; nt < 4; ++nt) {
        const size_t o = (size_t)(nt * 16 + lm) * 64
                       + (size_t)((((KS * 4 + lq) ^ (lm & 7))) << 3);
        f[nt] = *(const bf16x8_t*)(qp + o);
    }
}

template<int KS>
__device__ __forceinline__ void ks_mfma_hi(const bf16_t* Kh, int wr, int lm, int lq,
                                           const bf16x8_t (&qh)[4], f32x4 (&acc)[4][4])
{
    #pragma unroll
    for (int mt = 0; mt < 4; ++mt) {
        const int row = wr * 64 + mt * 16 + lm;
        const int off = row * 64 + ((((KS * 4 + lq) ^ (lm & 7))) << 3);
        const bf16x8_t ah = *(const bf16x8_t*)&Kh[off];
        #pragma unroll
        for (int nt = 0; nt < 4; ++nt)
            acc[mt][nt] = __builtin_amdgcn_mfma_f32_16x16x32_bf16(
                ah, qh[nt], acc[mt][nt], 0, 0, 0);
    }
}

// pass_b variant: per-wave 32p strip (mt<2), 64q tile
template<int KS>
__device__ __forceinline__ void ks_mfma_split2(const bf16_t* Kh, const bf16_t* Kl,
                                               int wr, int lm, int lq,
                                               const bf16x8_t (&qh)[4],
                                               const bf16x8_t (&ql)[4],
                                               f32x4 (&acc)[2][4])
{
    #pragma unroll
    for (int mt = 0; mt < 2; ++mt) {
        const int row = wr * 32 + mt * 16 + lm;
        const int off = row * 64 + ((((KS * 4 + lq) ^ (lm & 7))) << 3);
        const bf16x8_t ah = *(const bf16x8_t*)&Kh[off];
        const bf16x8_t al = *(const bf16x8_t*)&Kl[off];
        #pragma unroll
        for (int nt = 0; nt < 4; ++nt) {
            f32x4 a = acc[mt][nt];
            a = __builtin_amdgcn_mfma_f32_16x16x32_bf16(al, qh[nt], a, 0, 0, 0);
            a = __builtin_amdgcn_mfma_f32_16x16x32_bf16(ah, ql[nt], a, 0, 0, 0);
            a = __builtin_amdgcn_mfma_f32_16x16x32_bf16(ah, qh[nt], a, 0, 0, 0);
            acc[mt][nt] = a;
        }
    }
}

// ---------------- K3a: pass A — hi-plane bf16 score GEMM, (m,s) partials ----
// acc row-axis (lq,reg) = p; lane col-axis (lm) = q
__global__ __launch_bounds__(256, 4) void scores_pass_a(
    const bf16_t* __restrict__ qh_hi, const bf16_t* __restrict__ kp_hi,
    const int* __restrict__ mask, float* __restrict__ partials)
{
    __shared__ __align__(16) bf16_t Kh[128 * 64];   // kp_hi tile [p][c swz]
    __shared__ float redM[256];
    __shared__ float redS[256];
    const int z  = blockIdx.z;
    const int b  = z >> 3, n = z & 7;
    const int q0 = blockIdx.y * 128;
    const int p0 = blockIdx.x * 128;
    const int t  = threadIdx.x;
    const int wave = t >> 6, lane = t & 63;
    const int wr = wave >> 1, wc = wave & 1;        // wr: p-half, wc: q-half
    const int lm = lane & 15, lq = lane >> 4;
    const bool wave_active = (q0 + wc * 64) < NF;

    // stage kp_hi tile (pre-transposed, pre-swizzled -> pure 16B copies)
    const uint4* gb = (const uint4*)(kp_hi + ((size_t)(b * NH + n) * HW + p0) * 64);
    uint4* lb = (uint4*)Kh;
    #pragma unroll
    for (int i = 0; i < 4; ++i) lb[t + i * 256] = gb[t + i * 256];

    const bf16_t* qph = qh_hi + ((size_t)(b * NH + n) * NQP + q0 + wc * 64) * 64;
    bf16x8_t qf0[4];
    if (wave_active) load_qf<0>(qph, lm, lq, qf0);   // overlap staging drain
    __syncthreads();

    float tm = NEG_INF, ts = 0.f;
    if (wave_active) {
        f32x4 acc[4][4];
        const f32x4 zero4 = {0.f, 0.f, 0.f, 0.f};
        #pragma unroll
        for (int i = 0; i < 4; ++i)
            #pragma unroll
            for (int j = 0; j < 4; ++j) acc[i][j] = zero4;

        bf16x8_t qf1[4];
        load_qf<1>(qph, lm, lq, qf1);
        ks_mfma_hi<0>(Kh, wr, lm, lq, qf0, acc);
        ks_mfma_hi<1>(Kh, wr, lm, lq, qf1, acc);

        int4 mm4[4];
        #pragma unroll
        for (int mt = 0; mt < 4; ++mt)
            mm4[mt] = *(const int4*)&mask[b * HW + p0 + wr * 64 + mt * 16 + lq * 4];

        #pragma unroll
        for (int nt = 0; nt < 4; ++nt) {
            if (q0 + wc * 64 + nt * 16 + lm < NF) {
                #pragma unroll
                for (int mt = 0; mt < 4; ++mt)
                    #pragma unroll
                    for (int reg = 0; reg < 4; ++reg)
                        if (!((const int*)&mm4[mt])[reg])
                            tm = fmaxf(tm, acc[mt][nt][reg]);
            }
        }
        if (tm != NEG_INF) {
            #pragma unroll
            for (int nt = 0; nt < 4; ++nt) {
                if (q0 + wc * 64 + nt * 16 + lm < NF) {
                    #pragma unroll
                    for (int mt = 0; mt < 4; ++mt)
                        #pragma unroll
                        for (int reg = 0; reg < 4; ++reg)
                            if (!((const int*)&mm4[mt])[reg])
                                ts += __expf(acc[mt][nt][reg] - tm);
                }
            }
        }
    }

    redM[t] = tm; redS[t] = ts;
    __syncthreads();
    for (int off = 128; off > 0; off >>= 1) {
        if (t < off) {
            float m1 = redM[t],       s1 = redS[t];
            float m2 = redM[t + off], s2 = redS[t + off];
            float M = fmaxf(m1, m2);
            float s = (M == NEG_INF) ? 0.f
                      : (s1 * __expf(m1 - M) + s2 * __expf(m2 - M));
            redM[t] = M; redS[t] = s;
        }
        __syncthreads();
    }
    if (t == 0) {
        int lin = (z * gridDim.y + blockIdx.y) * gridDim.x + blockIdx.x;
        partials[2 * lin]     = redM[0];
        partials[2 * lin + 1] = redS[0];
    }
}

// ---------------- K4: merge partials per batch -> (M_b, 1/S_b) -------------
__global__ __launch_bounds__(256) void stats_kernel(
    const float* __restrict__ partials, float* __restrict__ stats, int nper)
{
    __shared__ float redM[256];
    __shared__ float redS[256];
    const int b = blockIdx.x, t = threadIdx.x;
    const float* p = partials + (size_t)b * nper * 2;
    float m = NEG_INF, s = 0.f;
    for (int i = t; i < nper; i += 256) {
        float m2 = p[2 * i], s2 = p[2 * i + 1];
        float M = fmaxf(m, m2);
        float ns = (M == NEG_INF) ? 0.f
                   : (s * __expf(m - M) + s2 * __expf(m2 - M));
        m = M; s = ns;
    }
    redM[t] = m; redS[t] = s;
    __syncthreads();
    for (int off = 128; off > 0; off >>= 1) {
        if (t < off) {
            float m1 = redM[t],       s1 = redS[t];
            float m2 = redM[t + off], s2 = redS[t + off];
            float M = fmaxf(m1, m2);
            float ns = (M == NEG_INF) ? 0.f
                       : (s1 * __expf(m1 - M) + s2 * __expf(m2 - M));
            redM[t] = M; redS[t] = ns;
        }
        __syncthreads();
    }
    if (t == 0) {
        stats[2 * b]     = redM[0];
        stats[2 * b + 1] = 1.0f / redS[0];
    }
}

// ---------------- K3b: pass B — split-bf16 score GEMM, write exp(s-M)/S ----
// 128p x 64q tile, 4 waves each owning a 32p strip -> acc[2][4] (32 VGPR),
// one ks-generation of q-fragments live at a time => fits 4 waves/SIMD.
__global__ __launch_bounds__(256, 4) void scores_pass_b(
    const bf16_t* __restrict__ qh_hi, const bf16_t* __restrict__ qh_lo,
    const bf16_t* __restrict__ kp_hi, const bf16_t* __restrict__ kp_lo,
    const int* __restrict__ mask, const float* __restrict__ stats,
    float* __restrict__ out)
{
    __shared__ __align__(16) bf16_t Kh[128 * 64];   // kp tiles [p][c swz]
    __shared__ __align__(16) bf16_t Kl[128 * 64];
    const int z  = blockIdx.z;
    const int b  = z >> 3, n = z & 7;
    const int q0 = blockIdx.y * 64;                 // 5 tiles of 64 (<=320)
    const int p0 = blockIdx.x * 128;
    const int t  = threadIdx.x;
    const int wave = t >> 6, lane = t & 63;
    const int wr = wave;                            // 32-row p strip per wave
    const int lm = lane & 15, lq = lane >> 4;

    const float M    = stats[2 * b];
    const float invS = stats[2 * b + 1];

    const size_t bbase = ((size_t)(b * NH + n) * HW + p0) * 64;
    const uint4* gbh = (const uint4*)(kp_hi + bbase);
    const uint4* gbl = (const uint4*)(kp_lo + bbase);
    #pragma unroll
    for (int i = 0; i < 4; ++i) {
        ((uint4*)Kh)[t + i * 256] = gbh[t + i * 256];
        ((uint4*)Kl)[t + i * 256] = gbl[t + i * 256];
    }

    const size_t qoff = ((size_t)(b * NH + n) * NQP + q0) * 64;
    const bf16_t* qph = qh_hi + qoff;
    const bf16_t* qpl = qh_lo + qoff;
    bf16x8_t qh0[4], ql0[4];
    load_qf<0>(qph, lm, lq, qh0);      // issue before the barrier drain
    load_qf<0>(qpl, lm, lq, ql0);
    __syncthreads();

    f32x4 acc[2][4];
    const f32x4 zero4 = {0.f, 0.f, 0.f, 0.f};
    #pragma unroll
    for (int i = 0; i < 2; ++i)
        #pragma unroll
        for (int j = 0; j < 4; ++j) acc[i][j] = zero4;

    ks_mfma_split2<0>(Kh, Kl, wr, lm, lq, qh0, ql0, acc);
    load_qf<1>(qph, lm, lq, qh0);      // reuse regs: ks0 fragments now dead
    load_qf<1>(qpl, lm, lq, ql0);
    ks_mfma_split2<1>(Kh, Kl, wr, lm, lq, qh0, ql0, acc);

    int4 mm4[2];
    #pragma unroll
    for (int mt = 0; mt < 2; ++mt)
        mm4[mt] = *(const int4*)&mask[b * HW + p0 + wr * 32 + mt * 16 + lq * 4];

    #pragma unroll
    for (int nt = 0; nt < 4; ++nt) {
        const int qg = q0 + nt * 16 + lm;
        if (qg < NF) {
            float* rowp = out + (size_t)(b * ROWS + qg * NH + n) * HW + p0 + wr * 32;
            #pragma unroll
            for (int mt = 0; mt < 2; ++mt) {
                f32x4 v;
                #pragma unroll
                for (int reg = 0; reg < 4; ++reg) {
                    const int msk = ((const int*)&mm4[mt])[reg];
                    v[reg] = msk ? 0.f : __expf(acc[mt][nt][reg] - M) * invS;
                }
                __builtin_nontemporal_store(v, (f32x4*)(rowp + mt * 16 + lq * 4));
            }
        }
    }
}

extern "C" void kernel_launch(void* const* d_in, const int* in_sizes, int n_in,
                              void* d_out, int out_size, void* d_ws, size_t ws_size,
                              hipStream_t stream) {
    const float* q    = (const float*)d_in[0];  // [4,300,512]
    const float* k    = (const float*)d_in[1];  // [4,512,80,80]
    const int*   mask = (const int*)  d_in[2];  // [4,80,80]
    const float* qw   = (const float*)d_in[3];  // [512,512]
    const float* qb   = (const float*)d_in[4];  // [512]
    const float* kw   = (const float*)d_in[5];  // [512,512]
    const float* kb   = (const float*)d_in[6];  // [512]
    float* out = (float*)d_out;                 // [4,1,2400,80,80]

    // workspace layout (bf16 planes + fp32 reductions), ~55.6 MB
    bf16_t* kp_hi = (bf16_t*)d_ws;
    bf16_t* kp_lo = kp_hi + (size_t)B_ * NH * HW * 64;
    bf16_t* qh_hi = kp_lo + (size_t)B_ * NH * HW * 64;
    bf16_t* qh_lo = qh_hi + (size_t)B_ * NH * NQP * 64;
    float* partials = (float*)(qh_lo + (size_t)B_ * NH * NQP * 64);
    float* stats    = partials + 2 * 4800;

    proj_kernel<<<1100, 256, 0, stream>>>(q, qw, qb, k, kw, kb,
                                          qh_hi, qh_lo, kp_hi, kp_lo);
    scores_pass_a<<<dim3(50, 3, 32), 256, 0, stream>>>(qh_hi, kp_hi, mask, partials);
    stats_kernel<<<4, 256, 0, stream>>>(partials, stats, 1200);
    scores_pass_b<<<dim3(50, 5, 32), 256, 0, stream>>>(qh_hi, qh_lo, kp_hi, kp_lo,
                                                       mask, stats, out);
}

// Round 4
// 481.913 us; speedup vs baseline: 1.1152x; 1.0014x over previous
//
#include <hip/hip_runtime.h>
#include <math.h>

#define B_    4
#define NF    300
#define QD    512
#define HID   512
#define NH    8
#define HD    64
#define HW    6400      // 80*80
#define ROWS  2400      // NF*NH
#define NQP   384       // padded q rows per (b,n) block (3 tiles of 128)
#define NORM_FACT 0.125f
#define NEG_INF (-INFINITY)
#define LDK   40        // padded LDS row (bf16) for kproj 32-wide k-chunks

typedef __bf16 bf16_t;
typedef __bf16 bf16x4_t __attribute__((ext_vector_type(4)));
typedef __bf16 bf16x8_t __attribute__((ext_vector_type(8)));
typedef float  f32x4    __attribute__((ext_vector_type(4)));

__device__ __forceinline__ void splitf(float x, bf16_t& h, bf16_t& l) {
    h = (bf16_t)x;
    l = (bf16_t)(x - (float)h);
}
// swizzle: permute 16B c-blocks within a 128B row by row&7 (conflict-free frags)
__device__ __forceinline__ int swz(int c, int row) {
    return (((c >> 3) ^ (row & 7)) << 3) | (c & 7);
}

// ---------------- K0: one-time W split -> Wh/Wl [e][d] linear bf16 planes --
// removes the redundant per-block W splitf from all 800 kproj blocks
__global__ __launch_bounds__(256) void wsplit_kernel(
    const float* __restrict__ kw, bf16_t* __restrict__ wh, bf16_t* __restrict__ wl)
{
    const int base = blockIdx.x * 2048 + threadIdx.x * 8;
    float4 v0 = *(const float4*)&kw[base];
    float4 v1 = *(const float4*)&kw[base + 4];
    bf16x8_t hv, lv; bf16_t h, l;
    splitf(v0.x, h, l); hv[0] = h; lv[0] = l;
    splitf(v0.y, h, l); hv[1] = h; lv[1] = l;
    splitf(v0.z, h, l); hv[2] = h; lv[2] = l;
    splitf(v0.w, h, l); hv[3] = h; lv[3] = l;
    splitf(v1.x, h, l); hv[4] = h; lv[4] = l;
    splitf(v1.y, h, l); hv[5] = h; lv[5] = l;
    splitf(v1.z, h, l); hv[6] = h; lv[6] = l;
    splitf(v1.w, h, l); hv[7] = h; lv[7] = l;
    *(bf16x8_t*)&wh[base] = hv;
    *(bf16x8_t*)&wl[base] = lv;
}

// ---------------- merged projection kernel bodies --------------------------
// qproj: q projection -> bf16 hi/lo planes [b][n][q][64c swz]
__device__ __forceinline__ void qproj_body(
    char* smem, int blk, const float* __restrict__ q,
    const float* __restrict__ qw, const float* __restrict__ qb,
    bf16_t* __restrict__ qh_hi, bf16_t* __restrict__ qh_lo)
{
    float (*qs)[QD] = (float (*)[QD])smem;
    const int r0    = blk * 4;                 // rows in (b*NF+q) space; NF%4==0
    const int b     = r0 / NF;
    const int qbase = r0 % NF;
    const int t     = threadIdx.x;
    #pragma unroll
    for (int row = 0; row < 4; ++row) {
        qs[row][t]       = q[(size_t)(r0 + row) * QD + t];
        qs[row][t + 256] = q[(size_t)(r0 + row) * QD + t + 256];
    }
    __syncthreads();
    #pragma unroll
    for (int eo = 0; eo < 2; ++eo) {
        const int e = t + eo * 256;
        const int n = e >> 6, c = e & 63;
        float a[4] = {0.f, 0.f, 0.f, 0.f};
        for (int d = 0; d < QD; d += 4) {
            float4 w = *(const float4*)&qw[(size_t)e * QD + d];
            #pragma unroll
            for (int row = 0; row < 4; ++row)
                a[row] += qs[row][d]*w.x + qs[row][d+1]*w.y
                        + qs[row][d+2]*w.z + qs[row][d+3]*w.w;
        }
        const float bias = qb[e];
        #pragma unroll
        for (int row = 0; row < 4; ++row) {
            const int qq = qbase + row;
            const float val = (a[row] + bias) * NORM_FACT;
            bf16_t h, l; splitf(val, h, l);
            size_t off = ((size_t)(b * NH + n) * NQP + qq) * 64 + swz(c, qq);
            qh_hi[off] = h; qh_lo[off] = l;
        }
    }
}

// kproj: k projection (M=p, N=e) -> bf16 hi/lo planes [b][n][p][64c swz]
// B-operand staging now reads pre-split Wh/Wl (pure copies, no splitf)
__device__ __forceinline__ void kproj_body(
    char* smem, int px, int ey, int b, const float* __restrict__ k,
    const bf16_t* __restrict__ wh, const bf16_t* __restrict__ wl,
    const float* __restrict__ kb,
    bf16_t* __restrict__ kp_hi, bf16_t* __restrict__ kp_lo)
{
    bf16_t (*Ah)[LDK] = (bf16_t (*)[LDK])(smem);            // K^T rows: [p][d]
    bf16_t (*Al)[LDK] = (bf16_t (*)[LDK])(smem + 10240);
    bf16_t (*Bh)[LDK] = (bf16_t (*)[LDK])(smem + 20480);    // W rows:   [e][d]
    bf16_t (*Bl)[LDK] = (bf16_t (*)[LDK])(smem + 30720);
    const int e0 = ey * 128;
    const int p0 = px * 128;
    const int t  = threadIdx.x;
    const int wave = t >> 6, lane = t & 63;
    const int wr = wave >> 1, wc = wave & 1;       // wr: p-half, wc: e-half
    const int lm = lane & 15, lq = lane >> 4;
    const float* kB = k + (size_t)b * QD * HW;

    f32x4 acc[4][4];
    const f32x4 zero4 = {0.f, 0.f, 0.f, 0.f};
    #pragma unroll
    for (int i = 0; i < 4; ++i)
        #pragma unroll
        for (int j = 0; j < 4; ++j) acc[i][j] = zero4;

    for (int d0 = 0; d0 < QD; d0 += 32) {
        // A = K^T: transpose-stage K[d][p] -> LDS [p][d] (split in-place)
        #pragma unroll
        for (int i = 0; i < 4; ++i) {
            int idx = t + i * 256;
            int p = idx & 127, db = (idx >> 7) << 2;
            bf16x4_t hv, lv;
            #pragma unroll
            for (int j = 0; j < 4; ++j) {
                float x = kB[(size_t)(d0 + db + j) * HW + p0 + p];
                bf16_t hx, lx; splitf(x, hx, lx);
                hv[j] = hx; lv[j] = lx;
            }
            *(bf16x4_t*)&Ah[p][db] = hv;
            *(bf16x4_t*)&Al[p][db] = lv;
        }
        // B = pre-split W planes: pure 16B loads + 8B LDS writes
        #pragma unroll
        for (int i = 0; i < 2; ++i) {
            int idx = t + i * 256;                  // 0..511
            int e = idx >> 2, d8 = (idx & 3) << 3;
            const size_t go = (size_t)(e0 + e) * QD + d0 + d8;
            union { bf16x8_t v8; bf16x4_t v4[2]; } uh, ul;
            uh.v8 = *(const bf16x8_t*)&wh[go];
            ul.v8 = *(const bf16x8_t*)&wl[go];
            *(bf16x4_t*)&Bh[e][d8]     = uh.v4[0];
            *(bf16x4_t*)&Bh[e][d8 + 4] = uh.v4[1];
            *(bf16x4_t*)&Bl[e][d8]     = ul.v4[0];
            *(bf16x4_t*)&Bl[e][d8 + 4] = ul.v4[1];
        }
        __syncthreads();

        bf16x8_t ah[4], al[4], bh[4], bl[4];
        #pragma unroll
        for (int mt = 0; mt < 4; ++mt) {
            int r = wr * 64 + mt * 16 + lm;
            ah[mt] = *(const bf16x8_t*)&Ah[r][lq * 8];
            al[mt] = *(const bf16x8_t*)&Al[r][lq * 8];
        }
        #pragma unroll
        for (int nt = 0; nt < 4; ++nt) {
            int c = wc * 64 + nt * 16 + lm;
            bh[nt] = *(const bf16x8_t*)&Bh[c][lq * 8];
            bl[nt] = *(const bf16x8_t*)&Bl[c][lq * 8];
        }
        #pragma unroll
        for (int mt = 0; mt < 4; ++mt)
            #pragma unroll
            for (int nt = 0; nt < 4; ++nt) {
                f32x4 a = acc[mt][nt];
                a = __builtin_amdgcn_mfma_f32_16x16x32_bf16(al[mt], bh[nt], a, 0, 0, 0);
                a = __builtin_amdgcn_mfma_f32_16x16x32_bf16(ah[mt], bl[nt], a, 0, 0, 0);
                a = __builtin_amdgcn_mfma_f32_16x16x32_bf16(ah[mt], bh[nt], a, 0, 0, 0);
                acc[mt][nt] = a;
            }
        __syncthreads();
    }

    // epilogue: lane axis = e (col), reg axis = p (row) -> c-contiguous stores
    #pragma unroll
    for (int nt = 0; nt < 4; ++nt) {
        const int e = e0 + wc * 64 + nt * 16 + lm;
        const int n = e >> 6;
        const int c = (nt * 16 + lm) & 63;     // == e & 63
        const float bias = kb[e];
        bf16_t* dh = kp_hi + (size_t)(b * NH + n) * HW * 64;
        bf16_t* dl = kp_lo + (size_t)(b * NH + n) * HW * 64;
        #pragma unroll
        for (int mt = 0; mt < 4; ++mt) {
            #pragma unroll
            for (int reg = 0; reg < 4; ++reg) {
                int p = p0 + wr * 64 + mt * 16 + lq * 4 + reg;
                float val = acc[mt][nt][reg] + bias;
                bf16_t h, l; splitf(val, h, l);
                size_t off = (size_t)p * 64 + swz(c, p);
                dh[off] = h; dl[off] = l;
            }
        }
    }
}

// merged: kproj blocks first (long pole), qproj blocks fill the tail
__global__ __launch_bounds__(256) void proj_kernel(
    const float* __restrict__ q, const float* __restrict__ qw,
    const float* __restrict__ qb, const float* __restrict__ k,
    const bf16_t* __restrict__ wh, const bf16_t* __restrict__ wl,
    const float* __restrict__ kb,
    bf16_t* __restrict__ qh_hi, bf16_t* __restrict__ qh_lo,
    bf16_t* __restrict__ kp_hi, bf16_t* __restrict__ kp_lo)
{
    __shared__ __align__(16) char smem[40960];
    const int bx = blockIdx.x;
    if (bx < 800) {
        kproj_body(smem, bx % 50, (bx / 50) % 4, bx / 200, k, wh, wl, kb,
                   kp_hi, kp_lo);
    } else {
        qproj_body(smem, bx - 800, q, qw, qb, qh_hi, qh_lo);
    }
}

// ---------------- score-pass helpers (operand-swapped: A=kp, B=qh) ---------
// qh fragment loads straight from global (L1/L2-hot, shared by 50 p-blocks)
template<int KS>
__device__ __forceinline__ void load_qf(const bf16_t* __restrict__ qp,
                                        int lm, int lq, bf16x8_t (&f)[4])
{
    #pragma unroll
    for (int nt = 0; nt < 4; ++nt) {
        const size_t o = (size_t)(nt * 16 + lm) * 64
                       + (size_t)((((KS * 4 + lq) ^ (lm & 7))) << 3);
        f[nt] = *(const bf16x8_t*)(qp + o);
    }
}

template<int KS>
__device__ __forceinline__ void ks_mfma_hi(const bf16_t* Kh, int wr, int lm, int lq,
                                           const bf16x8_t (&qh)[4], f32x4 (&acc)[4][4])
{
    #pragma unroll
    for (int mt = 0; mt < 4; ++mt) {
        const int row = wr * 64 + mt * 16 + lm;
        const int off = row * 64 + ((((KS * 4 + lq) ^ (lm & 7))) << 3);
        const bf16x8_t ah = *(const bf16x8_t*)&Kh[off];
        #pragma unroll
        for (int nt = 0; nt < 4; ++nt)
            acc[mt][nt] = __builtin_amdgcn_mfma_f32_16x16x32_bf16(
                ah, qh[nt], acc[mt][nt], 0, 0, 0);
    }
}

template<int KS>
__device__ __forceinline__ void ks_mfma_split(const bf16_t* Kh, const bf16_t* Kl,
                                              int wr, int lm, int lq,
                                              const bf16x8_t (&qh)[4],
                                              const bf16x8_t (&ql)[4],
                                              f32x4 (&acc)[4][4])
{
    #pragma unroll
    for (int mt = 0; mt < 4; ++mt) {
        const int row = wr * 64 + mt * 16 + lm;
        const int off = row * 64 + ((((KS * 4 + lq) ^ (lm & 7))) << 3);
        const bf16x8_t ah = *(const bf16x8_t*)&Kh[off];
        const bf16x8_t al = *(const bf16x8_t*)&Kl[off];
        #pragma unroll
        for (int nt = 0; nt < 4; ++nt) {
            f32x4 a = acc[mt][nt];
            a = __builtin_amdgcn_mfma_f32_16x16x32_bf16(al, qh[nt], a, 0, 0, 0);
            a = __builtin_amdgcn_mfma_f32_16x16x32_bf16(ah, ql[nt], a, 0, 0, 0);
            a = __builtin_amdgcn_mfma_f32_16x16x32_bf16(ah, qh[nt], a, 0, 0, 0);
            acc[mt][nt] = a;
        }
    }
}

// ---------------- K3a: pass A — hi-plane bf16 score GEMM, (m,s) partials ----
// acc row-axis (lq,reg) = p; lane col-axis (lm) = q
__global__ __launch_bounds__(256, 4) void scores_pass_a(
    const bf16_t* __restrict__ qh_hi, const bf16_t* __restrict__ kp_hi,
    const int* __restrict__ mask, float* __restrict__ partials)
{
    __shared__ __align__(16) bf16_t Kh[128 * 64];   // kp_hi tile [p][c swz]
    __shared__ float redM[256];
    __shared__ float redS[256];
    const int z  = blockIdx.z;
    const int b  = z >> 3, n = z & 7;
    const int q0 = blockIdx.y * 128;
    const int p0 = blockIdx.x * 128;
    const int t  = threadIdx.x;
    const int wave = t >> 6, lane = t & 63;
    const int wr = wave >> 1, wc = wave & 1;        // wr: p-half, wc: q-half
    const int lm = lane & 15, lq = lane >> 4;
    const bool wave_active = (q0 + wc * 64) < NF;

    // stage kp_hi tile (pre-transposed, pre-swizzled -> pure 16B copies)
    const uint4* gb = (const uint4*)(kp_hi + ((size_t)(b * NH + n) * HW + p0) * 64);
    uint4* lb = (uint4*)Kh;
    #pragma unroll
    for (int i = 0; i < 4; ++i) lb[t + i * 256] = gb[t + i * 256];

    const bf16_t* qph = qh_hi + ((size_t)(b * NH + n) * NQP + q0 + wc * 64) * 64;
    bf16x8_t qf0[4];
    if (wave_active) load_qf<0>(qph, lm, lq, qf0);   // overlap staging drain
    __syncthreads();

    float tm = NEG_INF, ts = 0.f;
    if (wave_active) {
        f32x4 acc[4][4];
        const f32x4 zero4 = {0.f, 0.f, 0.f, 0.f};
        #pragma unroll
        for (int i = 0; i < 4; ++i)
            #pragma unroll
            for (int j = 0; j < 4; ++j) acc[i][j] = zero4;

        bf16x8_t qf1[4];
        load_qf<1>(qph, lm, lq, qf1);
        ks_mfma_hi<0>(Kh, wr, lm, lq, qf0, acc);
        ks_mfma_hi<1>(Kh, wr, lm, lq, qf1, acc);

        int4 mm4[4];
        #pragma unroll
        for (int mt = 0; mt < 4; ++mt)
            mm4[mt] = *(const int4*)&mask[b * HW + p0 + wr * 64 + mt * 16 + lq * 4];

        #pragma unroll
        for (int nt = 0; nt < 4; ++nt) {
            if (q0 + wc * 64 + nt * 16 + lm < NF) {
                #pragma unroll
                for (int mt = 0; mt < 4; ++mt)
                    #pragma unroll
                    for (int reg = 0; reg < 4; ++reg)
                        if (!((const int*)&mm4[mt])[reg])
                            tm = fmaxf(tm, acc[mt][nt][reg]);
            }
        }
        if (tm != NEG_INF) {
            #pragma unroll
            for (int nt = 0; nt < 4; ++nt) {
                if (q0 + wc * 64 + nt * 16 + lm < NF) {
                    #pragma unroll
                    for (int mt = 0; mt < 4; ++mt)
                        #pragma unroll
                        for (int reg = 0; reg < 4; ++reg)
                            if (!((const int*)&mm4[mt])[reg])
                                ts += __expf(acc[mt][nt][reg] - tm);
                }
            }
        }
    }

    redM[t] = tm; redS[t] = ts;
    __syncthreads();
    for (int off = 128; off > 0; off >>= 1) {
        if (t < off) {
            float m1 = redM[t],       s1 = redS[t];
            float m2 = redM[t + off], s2 = redS[t + off];
            float M = fmaxf(m1, m2);
            float s = (M == NEG_INF) ? 0.f
                      : (s1 * __expf(m1 - M) + s2 * __expf(m2 - M));
            redM[t] = M; redS[t] = s;
        }
        __syncthreads();
    }
    if (t == 0) {
        int lin = (z * gridDim.y + blockIdx.y) * gridDim.x + blockIdx.x;
        partials[2 * lin]     = redM[0];
        partials[2 * lin + 1] = redS[0];
    }
}

// ---------------- K4: merge partials per batch -> (M_b, 1/S_b) -------------
__global__ __launch_bounds__(256) void stats_kernel(
    const float* __restrict__ partials, float* __restrict__ stats, int nper)
{
    __shared__ float redM[256];
    __shared__ float redS[256];
    const int b = blockIdx.x, t = threadIdx.x;
    const float* p = partials + (size_t)b * nper * 2;
    float m = NEG_INF, s = 0.f;
    for (int i = t; i < nper; i += 256) {
        float m2 = p[2 * i], s2 = p[2 * i + 1];
        float M = fmaxf(m, m2);
        float ns = (M == NEG_INF) ? 0.f
                   : (s * __expf(m - M) + s2 * __expf(m2 - M));
        m = M; s = ns;
    }
    redM[t] = m; redS[t] = s;
    __syncthreads();
    for (int off = 128; off > 0; off >>= 1) {
        if (t < off) {
            float m1 = redM[t],       s1 = redS[t];
            float m2 = redM[t + off], s2 = redS[t + off];
            float M = fmaxf(m1, m2);
            float ns = (M == NEG_INF) ? 0.f
                       : (s1 * __expf(m1 - M) + s2 * __expf(m2 - M));
            redM[t] = M; redS[t] = ns;
        }
        __syncthreads();
    }
    if (t == 0) {
        stats[2 * b]     = redM[0];
        stats[2 * b + 1] = 1.0f / redS[0];
    }
}

// ---------------- K3b: pass B — split-bf16 score GEMM, write exp(s-M)/S ----
// operand-swapped: acc reg-axis = p  =>  float4 nontemporal output stores
__global__ __launch_bounds__(256, 3) void scores_pass_b(
    const bf16_t* __restrict__ qh_hi, const bf16_t* __restrict__ qh_lo,
    const bf16_t* __restrict__ kp_hi, const bf16_t* __restrict__ kp_lo,
    const int* __restrict__ mask, const float* __restrict__ stats,
    float* __restrict__ out)
{
    __shared__ __align__(16) bf16_t Kh[128 * 64];   // kp tiles [p][c swz]
    __shared__ __align__(16) bf16_t Kl[128 * 64];
    const int z  = blockIdx.z;
    const int b  = z >> 3, n = z & 7;
    const int q0 = blockIdx.y * 128;
    const int p0 = blockIdx.x * 128;
    const int t  = threadIdx.x;
    const int wave = t >> 6, lane = t & 63;
    const int wr = wave >> 1, wc = wave & 1;        // wr: p-half, wc: q-half
    const int lm = lane & 15, lq = lane >> 4;
    const bool wave_active = (q0 + wc * 64) < NF;

    const float M    = stats[2 * b];
    const float invS = stats[2 * b + 1];

    const size_t bbase = ((size_t)(b * NH + n) * HW + p0) * 64;
    const uint4* gbh = (const uint4*)(kp_hi + bbase);
    const uint4* gbl = (const uint4*)(kp_lo + bbase);
    #pragma unroll
    for (int i = 0; i < 4; ++i) {
        ((uint4*)Kh)[t + i * 256] = gbh[t + i * 256];
        ((uint4*)Kl)[t + i * 256] = gbl[t + i * 256];
    }

    const size_t qoff = ((size_t)(b * NH + n) * NQP + q0 + wc * 64) * 64;
    const bf16_t* qph = qh_hi + qoff;
    const bf16_t* qpl = qh_lo + qoff;
    bf16x8_t qh0[4], ql0[4];
    if (wave_active) {                 // issue before the barrier drain
        load_qf<0>(qph, lm, lq, qh0);
        load_qf<0>(qpl, lm, lq, ql0);
    }
    __syncthreads();
    if (!wave_active) return;          // no further barriers in this kernel

    f32x4 acc[4][4];
    const f32x4 zero4 = {0.f, 0.f, 0.f, 0.f};
    #pragma unroll
    for (int i = 0; i < 4; ++i)
        #pragma unroll
        for (int j = 0; j < 4; ++j) acc[i][j] = zero4;

    bf16x8_t qh1[4], ql1[4];
    load_qf<1>(qph, lm, lq, qh1);      // latency covered by ks=0 MFMAs
    load_qf<1>(qpl, lm, lq, ql1);
    ks_mfma_split<0>(Kh, Kl, wr, lm, lq, qh0, ql0, acc);
    ks_mfma_split<1>(Kh, Kl, wr, lm, lq, qh1, ql1, acc);

    int4 mm4[4];
    #pragma unroll
    for (int mt = 0; mt < 4; ++mt)
        mm4[mt] = *(const int4*)&mask[b * HW + p0 + wr * 64 + mt * 16 + lq * 4];

    #pragma unroll
    for (int nt = 0; nt < 4; ++nt) {
        const int qg = q0 + wc * 64 + nt * 16 + lm;
        if (qg < NF) {
            float* rowp = out + (size_t)(b * ROWS + qg * NH + n) * HW + p0 + wr * 64;
            #pragma unroll
            for (int mt = 0; mt < 4; ++mt) {
                f32x4 v;
                #pragma unroll
                for (int reg = 0; reg < 4; ++reg) {
                    const int msk = ((const int*)&mm4[mt])[reg];
                    v[reg] = msk ? 0.f : __expf(acc[mt][nt][reg] - M) * invS;
                }
                __builtin_nontemporal_store(v, (f32x4*)(rowp + mt * 16 + lq * 4));
            }
        }
    }
}

extern "C" void kernel_launch(void* const* d_in, const int* in_sizes, int n_in,
                              void* d_out, int out_size, void* d_ws, size_t ws_size,
                              hipStream_t stream) {
    const float* q    = (const float*)d_in[0];  // [4,300,512]
    const float* k    = (const float*)d_in[1];  // [4,512,80,80]
    const int*   mask = (const int*)  d_in[2];  // [4,80,80]
    const float* qw   = (const float*)d_in[3];  // [512,512]
    const float* qb   = (const float*)d_in[4];  // [512]
    const float* kw   = (const float*)d_in[5];  // [512,512]
    const float* kb   = (const float*)d_in[6];  // [512]
    float* out = (float*)d_out;                 // [4,1,2400,80,80]

    // workspace layout (bf16 planes + fp32 reductions), ~55.6 MB
    bf16_t* kp_hi = (bf16_t*)d_ws;
    bf16_t* kp_lo = kp_hi + (size_t)B_ * NH * HW * 64;
    bf16_t* qh_hi = kp_lo + (size_t)B_ * NH * HW * 64;
    bf16_t* qh_lo = qh_hi + (size_t)B_ * NH * NQP * 64;
    float* partials = (float*)(qh_lo + (size_t)B_ * NH * NQP * 64);
    float* stats    = partials + 2 * 4800;

    // W split planes live in d_out scratch (1 MB of 245.8 MB); consumed by
    // proj_kernel before scores_pass_b overwrites out (stream-ordered).
    bf16_t* wh = (bf16_t*)d_out;
    bf16_t* wl = wh + (size_t)HID * QD;

    wsplit_kernel<<<128, 256, 0, stream>>>(kw, wh, wl);
    proj_kernel<<<1100, 256, 0, stream>>>(q, qw, qb, k, wh, wl, kb,
                                          qh_hi, qh_lo, kp_hi, kp_lo);
    scores_pass_a<<<dim3(50, 3, 32), 256, 0, stream>>>(qh_hi, kp_hi, mask, partials);
    stats_kernel<<<4, 256, 0, stream>>>(partials, stats, 1200);
    scores_pass_b<<<dim3(50, 3, 32), 256, 0, stream>>>(qh_hi, qh_lo, kp_hi, kp_lo,
                                                       mask, stats, out);
}

// Round 7
// 476.909 us; speedup vs baseline: 1.1269x; 1.0105x over previous
//
#include <hip/hip_runtime.h>
#include <math.h>

#define B_    4
#define NF    300
#define QD    512
#define HID   512
#define NH    8
#define HD    64
#define HW    6400      // 80*80
#define ROWS  2400      // NF*NH
#define NQP   384       // padded q rows per (b,n) block (3 tiles of 128)
#define NORM_FACT 0.125f
#define NEG_INF (-INFINITY)
#define LDK   40        // padded LDS row (bf16) for kproj 32-wide k-chunks

typedef __bf16 bf16_t;
typedef __bf16 bf16x4_t __attribute__((ext_vector_type(4)));
typedef __bf16 bf16x8_t __attribute__((ext_vector_type(8)));
typedef float  f32x4    __attribute__((ext_vector_type(4)));

__device__ __forceinline__ void splitf(float x, bf16_t& h, bf16_t& l) {
    h = (bf16_t)x;
    l = (bf16_t)(x - (float)h);
}
// swizzle: permute 16B c-blocks within a 128B row by row&7 (conflict-free frags)
__device__ __forceinline__ int swz(int c, int row) {
    return (((c >> 3) ^ (row & 7)) << 3) | (c & 7);
}

// ---------------- merged projection kernel bodies --------------------------
// qproj: q projection -> bf16 hi/lo planes [b][n][q][64c swz]
__device__ __forceinline__ void qproj_body(
    char* smem, int blk, const float* __restrict__ q,
    const float* __restrict__ qw, const float* __restrict__ qb,
    bf16_t* __restrict__ qh_hi, bf16_t* __restrict__ qh_lo)
{
    float (*qs)[QD] = (float (*)[QD])smem;
    const int r0    = blk * 4;                 // rows in (b*NF+q) space; NF%4==0
    const int b     = r0 / NF;
    const int qbase = r0 % NF;
    const int t     = threadIdx.x;
    #pragma unroll
    for (int row = 0; row < 4; ++row) {
        qs[row][t]       = q[(size_t)(r0 + row) * QD + t];
        qs[row][t + 256] = q[(size_t)(r0 + row) * QD + t + 256];
    }
    __syncthreads();
    #pragma unroll
    for (int eo = 0; eo < 2; ++eo) {
        const int e = t + eo * 256;
        const int n = e >> 6, c = e & 63;
        float a[4] = {0.f, 0.f, 0.f, 0.f};
        for (int d = 0; d < QD; d += 4) {
            float4 w = *(const float4*)&qw[(size_t)e * QD + d];
            #pragma unroll
            for (int row = 0; row < 4; ++row)
                a[row] += qs[row][d]*w.x + qs[row][d+1]*w.y
                        + qs[row][d+2]*w.z + qs[row][d+3]*w.w;
        }
        const float bias = qb[e];
        #pragma unroll
        for (int row = 0; row < 4; ++row) {
            const int qq = qbase + row;
            const float val = (a[row] + bias) * NORM_FACT;
            bf16_t h, l; splitf(val, h, l);
            size_t off = ((size_t)(b * NH + n) * NQP + qq) * 64 + swz(c, qq);
            qh_hi[off] = h; qh_lo[off] = l;
        }
    }
}

// kproj: k projection (M=p, N=e) -> bf16 hi/lo planes [b][n][p][64c swz]
__device__ __forceinline__ void kproj_body(
    char* smem, int px, int ey, int b, const float* __restrict__ k,
    const float* __restrict__ kw, const float* __restrict__ kb,
    bf16_t* __restrict__ kp_hi, bf16_t* __restrict__ kp_lo)
{
    bf16_t (*Ah)[LDK] = (bf16_t (*)[LDK])(smem);            // K^T rows: [p][d]
    bf16_t (*Al)[LDK] = (bf16_t (*)[LDK])(smem + 10240);
    bf16_t (*Bh)[LDK] = (bf16_t (*)[LDK])(smem + 20480);    // W rows:   [e][d]
    bf16_t (*Bl)[LDK] = (bf16_t (*)[LDK])(smem + 30720);
    const int e0 = ey * 128;
    const int p0 = px * 128;
    const int t  = threadIdx.x;
    const int wave = t >> 6, lane = t & 63;
    const int wr = wave >> 1, wc = wave & 1;       // wr: p-half, wc: e-half
    const int lm = lane & 15, lq = lane >> 4;
    const float* kB = k + (size_t)b * QD * HW;

    f32x4 acc[4][4];
    const f32x4 zero4 = {0.f, 0.f, 0.f, 0.f};
    #pragma unroll
    for (int i = 0; i < 4; ++i)
        #pragma unroll
        for (int j = 0; j < 4; ++j) acc[i][j] = zero4;

    for (int d0 = 0; d0 < QD; d0 += 32) {
        // A = K^T: transpose-stage K[d][p] -> LDS [p][d]
        #pragma unroll
        for (int i = 0; i < 4; ++i) {
            int idx = t + i * 256;
            int p = idx & 127, db = (idx >> 7) << 2;
            bf16x4_t hv, lv;
            #pragma unroll
            for (int j = 0; j < 4; ++j) {
                float x = kB[(size_t)(d0 + db + j) * HW + p0 + p];
                bf16_t hx, lx; splitf(x, hx, lx);
                hv[j] = hx; lv[j] = lx;
            }
            *(bf16x4_t*)&Ah[p][db] = hv;
            *(bf16x4_t*)&Al[p][db] = lv;
        }
        // B = W: rows are already d-contiguous
        #pragma unroll
        for (int i = 0; i < 4; ++i) {
            int idx = t + i * 256;
            int e = idx >> 3, dp = (idx & 7) << 2;
            float4 v = *(const float4*)&kw[(size_t)(e0 + e) * QD + d0 + dp];
            bf16x4_t hv, lv; bf16_t hx, lx;
            splitf(v.x, hx, lx); hv[0] = hx; lv[0] = lx;
            splitf(v.y, hx, lx); hv[1] = hx; lv[1] = lx;
            splitf(v.z, hx, lx); hv[2] = hx; lv[2] = lx;
            splitf(v.w, hx, lx); hv[3] = hx; lv[3] = lx;
            *(bf16x4_t*)&Bh[e][dp] = hv;
            *(bf16x4_t*)&Bl[e][dp] = lv;
        }
        __syncthreads();

        bf16x8_t ah[4], al[4], bh[4], bl[4];
        #pragma unroll
        for (int mt = 0; mt < 4; ++mt) {
            int r = wr * 64 + mt * 16 + lm;
            ah[mt] = *(const bf16x8_t*)&Ah[r][lq * 8];
            al[mt] = *(const bf16x8_t*)&Al[r][lq * 8];
        }
        #pragma unroll
        for (int nt = 0; nt < 4; ++nt) {
            int c = wc * 64 + nt * 16 + lm;
            bh[nt] = *(const bf16x8_t*)&Bh[c][lq * 8];
            bl[nt] = *(const bf16x8_t*)&Bl[c][lq * 8];
        }
        #pragma unroll
        for (int mt = 0; mt < 4; ++mt)
            #pragma unroll
            for (int nt = 0; nt < 4; ++nt) {
                f32x4 a = acc[mt][nt];
                a = __builtin_amdgcn_mfma_f32_16x16x32_bf16(al[mt], bh[nt], a, 0, 0, 0);
                a = __builtin_amdgcn_mfma_f32_16x16x32_bf16(ah[mt], bl[nt], a, 0, 0, 0);
                a = __builtin_amdgcn_mfma_f32_16x16x32_bf16(ah[mt], bh[nt], a, 0, 0, 0);
                acc[mt][nt] = a;
            }
        __syncthreads();
    }

    // epilogue: lane axis = e (col), reg axis = p (row) -> c-contiguous stores
    #pragma unroll
    for (int nt = 0; nt < 4; ++nt) {
        const int e = e0 + wc * 64 + nt * 16 + lm;
        const int n = e >> 6;
        const int c = (nt * 16 + lm) & 63;     // == e & 63
        const float bias = kb[e];
        bf16_t* dh = kp_hi + (size_t)(b * NH + n) * HW * 64;
        bf16_t* dl = kp_lo + (size_t)(b * NH + n) * HW * 64;
        #pragma unroll
        for (int mt = 0; mt < 4; ++mt) {
            #pragma unroll
            for (int reg = 0; reg < 4; ++reg) {
                int p = p0 + wr * 64 + mt * 16 + lq * 4 + reg;
                float val = acc[mt][nt][reg] + bias;
                bf16_t h, l; splitf(val, h, l);
                size_t off = (size_t)p * 64 + swz(c, p);
                dh[off] = h; dl[off] = l;
            }
        }
    }
}

// merged: kproj blocks first (long pole), qproj blocks fill the tail
__global__ __launch_bounds__(256) void proj_kernel(
    const float* __restrict__ q, const float* __restrict__ qw,
    const float* __restrict__ qb, const float* __restrict__ k,
    const float* __restrict__ kw, const float* __restrict__ kb,
    bf16_t* __restrict__ qh_hi, bf16_t* __restrict__ qh_lo,
    bf16_t* __restrict__ kp_hi, bf16_t* __restrict__ kp_lo)
{
    __shared__ __align__(16) char smem[40960];
    const int bx = blockIdx.x;
    if (bx < 800) {
        kproj_body(smem, bx % 50, (bx / 50) % 4, bx / 200, k, kw, kb, kp_hi, kp_lo);
    } else {
        qproj_body(smem, bx - 800, q, qw, qb, qh_hi, qh_lo);
    }
}

// ---------------- score-pass helpers (operand-swapped: A=kp, B=qh) ---------
// qh fragment loads straight from global (L1/L2-hot, shared by 50 p-blocks)
template<int KS>
__device__ __forceinline__ void load_qf(const bf16_t* __restrict__ qp,
                                        int lm, int lq, bf16x8_t (&f)[4])
{
    #pragma unroll
    for (int nt = 0; nt < 4; ++nt) {
        const size_t o = (size_t)(nt * 16 + lm) * 64
                       + (size_t)((((KS * 4 + lq) ^ (lm & 7))) << 3);
        f[nt] = *(const bf16x8_t*)(qp + o);
    }
}

template<int KS>
__device__ __forceinline__ void ks_mfma_hi(const bf16_t* Kh, int wr, int lm, int lq,
                                           const bf16x8_t (&qh)[4], f32x4 (&acc)[4][4])
{
    #pragma unroll
    for (int mt = 0; mt < 4; ++mt) {
        const int row = wr * 64 + mt * 16 + lm;
        const int off = row * 64 + ((((KS * 4 + lq) ^ (lm & 7))) << 3);
        const bf16x8_t ah = *(const bf16x8_t*)&Kh[off];
        #pragma unroll
        for (int nt = 0; nt < 4; ++nt)
            acc[mt][nt] = __builtin_amdgcn_mfma_f32_16x16x32_bf16(
                ah, qh[nt], acc[mt][nt], 0, 0, 0);
    }
}

template<int KS>
__device__ __forceinline__ void ks_mfma_split(const bf16_t* Kh, const bf16_t* Kl,
                                              int wr, int lm, int lq,
                                              const bf16x8_t (&qh)[4],
                                              const bf16x8_t (&ql)[4],
                                              f32x4 (&acc)[4][4])
{
    #pragma unroll
    for (int mt = 0; mt < 4; ++mt) {
        const int row = wr * 64 + mt * 16 + lm;
        const int off = row * 64 + ((((KS * 4 + lq) ^ (lm & 7))) << 3);
        const bf16x8_t ah = *(const bf16x8_t*)&Kh[off];
        const bf16x8_t al = *(const bf16x8_t*)&Kl[off];
        #pragma unroll
        for (int nt = 0; nt < 4; ++nt) {
            f32x4 a = acc[mt][nt];
            a = __builtin_amdgcn_mfma_f32_16x16x32_bf16(al, qh[nt], a, 0, 0, 0);
            a = __builtin_amdgcn_mfma_f32_16x16x32_bf16(ah, ql[nt], a, 0, 0, 0);
            a = __builtin_amdgcn_mfma_f32_16x16x32_bf16(ah, qh[nt], a, 0, 0, 0);
            acc[mt][nt] = a;
        }
    }
}

// ---------------- K3a: pass A — hi-plane bf16 score GEMM, (m,s) partials ----
// acc row-axis (lq,reg) = p; lane col-axis (lm) = q
__global__ __launch_bounds__(256, 4) void scores_pass_a(
    const bf16_t* __restrict__ qh_hi, const bf16_t* __restrict__ kp_hi,
    const int* __restrict__ mask, float* __restrict__ partials)
{
    __shared__ __align__(16) bf16_t Kh[128 * 64];   // kp_hi tile [p][c swz]
    __shared__ float redM[256];
    __shared__ float redS[256];
    const int z  = blockIdx.z;
    const int b  = z >> 3, n = z & 7;
    const int q0 = blockIdx.y * 128;
    const int p0 = blockIdx.x * 128;
    const int t  = threadIdx.x;
    const int wave = t >> 6, lane = t & 63;
    const int wr = wave >> 1, wc = wave & 1;        // wr: p-half, wc: q-half
    const int lm = lane & 15, lq = lane >> 4;
    const bool wave_active = (q0 + wc * 64) < NF;

    // stage kp_hi tile (pre-transposed, pre-swizzled -> pure 16B copies)
    const uint4* gb = (const uint4*)(kp_hi + ((size_t)(b * NH + n) * HW + p0) * 64);
    uint4* lb = (uint4*)Kh;
    #pragma unroll
    for (int i = 0; i < 4; ++i) lb[t + i * 256] = gb[t + i * 256];

    const bf16_t* qph = qh_hi + ((size_t)(b * NH + n) * NQP + q0 + wc * 64) * 64;
    bf16x8_t qf0[4];
    if (wave_active) load_qf<0>(qph, lm, lq, qf0);   // overlap staging drain
    __syncthreads();

    float tm = NEG_INF, ts = 0.f;
    if (wave_active) {
        f32x4 acc[4][4];
        const f32x4 zero4 = {0.f, 0.f, 0.f, 0.f};
        #pragma unroll
        for (int i = 0; i < 4; ++i)
            #pragma unroll
            for (int j = 0; j < 4; ++j) acc[i][j] = zero4;

        bf16x8_t qf1[4];
        load_qf<1>(qph, lm, lq, qf1);
        ks_mfma_hi<0>(Kh, wr, lm, lq, qf0, acc);
        ks_mfma_hi<1>(Kh, wr, lm, lq, qf1, acc);

        int4 mm4[4];
        #pragma unroll
        for (int mt = 0; mt < 4; ++mt)
            mm4[mt] = *(const int4*)&mask[b * HW + p0 + wr * 64 + mt * 16 + lq * 4];

        #pragma unroll
        for (int nt = 0; nt < 4; ++nt) {
            if (q0 + wc * 64 + nt * 16 + lm < NF) {
                #pragma unroll
                for (int mt = 0; mt < 4; ++mt)
                    #pragma unroll
                    for (int reg = 0; reg < 4; ++reg)
                        if (!((const int*)&mm4[mt])[reg])
                            tm = fmaxf(tm, acc[mt][nt][reg]);
            }
        }
        if (tm != NEG_INF) {
            #pragma unroll
            for (int nt = 0; nt < 4; ++nt) {
                if (q0 + wc * 64 + nt * 16 + lm < NF) {
                    #pragma unroll
                    for (int mt = 0; mt < 4; ++mt)
                        #pragma unroll
                        for (int reg = 0; reg < 4; ++reg)
                            if (!((const int*)&mm4[mt])[reg])
                                ts += __expf(acc[mt][nt][reg] - tm);
                }
            }
        }
    }

    redM[t] = tm; redS[t] = ts;
    __syncthreads();
    for (int off = 128; off > 0; off >>= 1) {
        if (t < off) {
            float m1 = redM[t],       s1 = redS[t];
            float m2 = redM[t + off], s2 = redS[t + off];
            float M = fmaxf(m1, m2);
            float s = (M == NEG_INF) ? 0.f
                      : (s1 * __expf(m1 - M) + s2 * __expf(m2 - M));
            redM[t] = M; redS[t] = s;
        }
        __syncthreads();
    }
    if (t == 0) {
        int lin = (z * gridDim.y + blockIdx.y) * gridDim.x + blockIdx.x;
        partials[2 * lin]     = redM[0];
        partials[2 * lin + 1] = redS[0];
    }
}

// ---------------- K4: merge partials per batch -> (M_b, 1/S_b) -------------
__global__ __launch_bounds__(256) void stats_kernel(
    const float* __restrict__ partials, float* __restrict__ stats, int nper)
{
    __shared__ float redM[256];
    __shared__ float redS[256];
    const int b = blockIdx.x, t = threadIdx.x;
    const float* p = partials + (size_t)b * nper * 2;
    float m = NEG_INF, s = 0.f;
    for (int i = t; i < nper; i += 256) {
        float m2 = p[2 * i], s2 = p[2 * i + 1];
        float M = fmaxf(m, m2);
        float ns = (M == NEG_INF) ? 0.f
                   : (s * __expf(m - M) + s2 * __expf(m2 - M));
        m = M; s = ns;
    }
    redM[t] = m; redS[t] = s;
    __syncthreads();
    for (int off = 128; off > 0; off >>= 1) {
        if (t < off) {
            float m1 = redM[t],       s1 = redS[t];
            float m2 = redM[t + off], s2 = redS[t + off];
            float M = fmaxf(m1, m2);
            float ns = (M == NEG_INF) ? 0.f
                       : (s1 * __expf(m1 - M) + s2 * __expf(m2 - M));
            redM[t] = M; redS[t] = ns;
        }
        __syncthreads();
    }
    if (t == 0) {
        stats[2 * b]     = redM[0];
        stats[2 * b + 1] = 1.0f / redS[0];
    }
}

// ---------------- K3b: pass B — split-bf16 score GEMM, write exp(s-M)/S ----
// operand-swapped: acc reg-axis = p  =>  float4 nontemporal output stores
__global__ __launch_bounds__(256, 3) void scores_pass_b(
    const bf16_t* __restrict__ qh_hi, const bf16_t* __restrict__ qh_lo,
    const bf16_t* __restrict__ kp_hi, const bf16_t* __restrict__ kp_lo,
    const int* __restrict__ mask, const float* __restrict__ stats,
    float* __restrict__ out)
{
    __shared__ __align__(16) bf16_t Kh[128 * 64];   // kp tiles [p][c swz]
    __shared__ __align__(16) bf16_t Kl[128 * 64];
    const int z  = blockIdx.z;
    const int b  = z >> 3, n = z & 7;
    const int q0 = blockIdx.y * 128;
    const int p0 = blockIdx.x * 128;
    const int t  = threadIdx.x;
    const int wave = t >> 6, lane = t & 63;
    const int wr = wave >> 1, wc = wave & 1;        // wr: p-half, wc: q-half
    const int lm = lane & 15, lq = lane >> 4;
    const bool wave_active = (q0 + wc * 64) < NF;

    const float M    = stats[2 * b];
    const float invS = stats[2 * b + 1];

    const size_t bbase = ((size_t)(b * NH + n) * HW + p0) * 64;
    const uint4* gbh = (const uint4*)(kp_hi + bbase);
    const uint4* gbl = (const uint4*)(kp_lo + bbase);
    #pragma unroll
    for (int i = 0; i < 4; ++i) {
        ((uint4*)Kh)[t + i * 256] = gbh[t + i * 256];
        ((uint4*)Kl)[t + i * 256] = gbl[t + i * 256];
    }

    const size_t qoff = ((size_t)(b * NH + n) * NQP + q0 + wc * 64) * 64;
    const bf16_t* qph = qh_hi + qoff;
    const bf16_t* qpl = qh_lo + qoff;
    bf16x8_t qh0[4], ql0[4];
    if (wave_active) {                 // issue before the barrier drain
        load_qf<0>(qph, lm, lq, qh0);
        load_qf<0>(qpl, lm, lq, ql0);
    }
    __syncthreads();
    if (!wave_active) return;          // no further barriers in this kernel

    f32x4 acc[4][4];
    const f32x4 zero4 = {0.f, 0.f, 0.f, 0.f};
    #pragma unroll
    for (int i = 0; i < 4; ++i)
        #pragma unroll
        for (int j = 0; j < 4; ++j) acc[i][j] = zero4;

    bf16x8_t qh1[4], ql1[4];
    load_qf<1>(qph, lm, lq, qh1);      // latency covered by ks=0 MFMAs
    load_qf<1>(qpl, lm, lq, ql1);
    ks_mfma_split<0>(Kh, Kl, wr, lm, lq, qh0, ql0, acc);
    ks_mfma_split<1>(Kh, Kl, wr, lm, lq, qh1, ql1, acc);

    int4 mm4[4];
    #pragma unroll
    for (int mt = 0; mt < 4; ++mt)
        mm4[mt] = *(const int4*)&mask[b * HW + p0 + wr * 64 + mt * 16 + lq * 4];

    #pragma unroll
    for (int nt = 0; nt < 4; ++nt) {
        const int qg = q0 + wc * 64 + nt * 16 + lm;
        if (qg < NF) {
            float* rowp = out + (size_t)(b * ROWS + qg * NH + n) * HW + p0 + wr * 64;
            #pragma unroll
            for (int mt = 0; mt < 4; ++mt) {
                f32x4 v;
                #pragma unroll
                for (int reg = 0; reg < 4; ++reg) {
                    const int msk = ((const int*)&mm4[mt])[reg];
                    v[reg] = msk ? 0.f : __expf(acc[mt][nt][reg] - M) * invS;
                }
                __builtin_nontemporal_store(v, (f32x4*)(rowp + mt * 16 + lq * 4));
            }
        }
    }
}

extern "C" void kernel_launch(void* const* d_in, const int* in_sizes, int n_in,
                              void* d_out, int out_size, void* d_ws, size_t ws_size,
                              hipStream_t stream) {
    const float* q    = (const float*)d_in[0];  // [4,300,512]
    const float* k    = (const float*)d_in[1];  // [4,512,80,80]
    const int*   mask = (const int*)  d_in[2];  // [4,80,80]
    const float* qw   = (const float*)d_in[3];  // [512,512]
    const float* qb   = (const float*)d_in[4];  // [512]
    const float* kw   = (const float*)d_in[5];  // [512,512]
    const float* kb   = (const float*)d_in[6];  // [512]
    float* out = (float*)d_out;                 // [4,1,2400,80,80]

    // workspace layout (bf16 planes + fp32 reductions), ~55.6 MB
    bf16_t* kp_hi = (bf16_t*)d_ws;
    bf16_t* kp_lo = kp_hi + (size_t)B_ * NH * HW * 64;
    bf16_t* qh_hi = kp_lo + (size_t)B_ * NH * HW * 64;
    bf16_t* qh_lo = qh_hi + (size_t)B_ * NH * NQP * 64;
    float* partials = (float*)(qh_lo + (size_t)B_ * NH * NQP * 64);
    float* stats    = partials + 2 * 4800;

    proj_kernel<<<1100, 256, 0, stream>>>(q, qw, qb, k, kw, kb,
                                          qh_hi, qh_lo, kp_hi, kp_lo);
    scores_pass_a<<<dim3(50, 3, 32), 256, 0, stream>>>(qh_hi, kp_hi, mask, partials);
    stats_kernel<<<4, 256, 0, stream>>>(partials, stats, 1200);
    scores_pass_b<<<dim3(50, 3, 32), 256, 0, stream>>>(qh_hi, qh_lo, kp_hi, kp_lo,
                                                       mask, stats, out);
}